// Round 1
// baseline (35.862 us; speedup 1.0000x reference)
//
#include <hip/hip_runtime.h>

// Problem constants (from reference: x [16, 32, 64, 32, 32] f32)
constexpr int T_DIM   = 16;
constexpr int B_DIM   = 32;
constexpr int FEAT    = 64 * 32 * 32;   // 65536 features per (t,b)
constexpr int THREADS = 256;
constexpr int NCHUNK  = 32;             // blocks per b
constexpr int FPB     = FEAT / NCHUNK;  // 2048 features per block
constexpr int ITERS   = FPB / (THREADS * 4); // 2 float4 groups per thread

// Pass 1: one read of x. Each thread owns float4 feature groups; keeps the
// 16 relu-cumsums in registers; accumulates per-t sum(r^2) and sum(s[t]*s[15]).
__global__ __launch_bounds__(THREADS) void snn_pass1(
    const float* __restrict__ x, float* __restrict__ partial) {
    const int b     = blockIdx.x;   // 0..31
    const int chunk = blockIdx.y;   // 0..31
    const int tid   = threadIdx.x;

    float accA[T_DIM];  // sum over owned features of (s[t]/(t+1))^2
    float accB[T_DIM];  // sum over owned features of s[t]*s[15] / ((t+1)*16)
#pragma unroll
    for (int t = 0; t < T_DIM; ++t) { accA[t] = 0.f; accB[t] = 0.f; }

    const size_t base_b   = (size_t)b * FEAT;
    const size_t tstride4 = (size_t)B_DIM * FEAT / 4;  // t-stride in float4 units

    for (int it = 0; it < ITERS; ++it) {
        const int f = chunk * FPB + (it * THREADS + tid) * 4;
        const float4* p = reinterpret_cast<const float4*>(x + base_b + f);

        float4 s[T_DIM];
        float4 run = make_float4(0.f, 0.f, 0.f, 0.f);
#pragma unroll
        for (int t = 0; t < T_DIM; ++t) {
            float4 v = p[(size_t)t * tstride4];
            run.x += fmaxf(v.x, 0.f);
            run.y += fmaxf(v.y, 0.f);
            run.z += fmaxf(v.z, 0.f);
            run.w += fmaxf(v.w, 0.f);
            s[t] = run;
        }
        const float4 sf = run;  // s[15]
#pragma unroll
        for (int t = 0; t < T_DIM; ++t) {
            const float invt = 1.f / (float)(t + 1);
            const float4 st  = s[t];
            accA[t] += (st.x * st.x + st.y * st.y + st.z * st.z + st.w * st.w)
                       * (invt * invt);
            accB[t] += (st.x * sf.x + st.y * sf.y + st.z * sf.z + st.w * sf.w)
                       * (invt * (1.f / 16.f));
        }
    }

    // Wave-level shuffle reduction (64 lanes), then cross-wave via LDS.
    const int lane = tid & 63;
    const int wave = tid >> 6;
#pragma unroll
    for (int t = 0; t < T_DIM; ++t) {
        float a  = accA[t];
        float bb = accB[t];
#pragma unroll
        for (int off = 32; off; off >>= 1) {
            a  += __shfl_down(a, off, 64);
            bb += __shfl_down(bb, off, 64);
        }
        accA[t] = a;
        accB[t] = bb;
    }

    __shared__ float red[4][32];
    if (lane == 0) {
#pragma unroll
        for (int t = 0; t < T_DIM; ++t) {
            red[wave][t]          = accA[t];
            red[wave][16 + t]     = accB[t];
        }
    }
    __syncthreads();
    if (tid < 32) {
        float acc = red[0][tid] + red[1][tid] + red[2][tid] + red[3][tid];
        partial[((size_t)b * NCHUNK + chunk) * 32 + tid] = acc;
    }
}

// Pass 2: reduce chunks, finalize per-b scalar.
__global__ __launch_bounds__(64) void snn_finalize(
    const float* __restrict__ partial, float* __restrict__ out) {
    const int b   = blockIdx.x;   // 0..31
    const int tid = threadIdx.x;  // 64 threads

    __shared__ float sA[16];
    __shared__ float sB[16];
    if (tid < 32) {
        float acc = 0.f;
        for (int c = 0; c < NCHUNK; ++c)
            acc += partial[((size_t)b * NCHUNK + c) * 32 + tid];
        if (tid < 16) sA[tid] = acc;
        else          sB[tid - 16] = acc;
    }
    __syncthreads();
    if (tid == 0) {
        const float n15 = sqrtf(sA[15] + 1e-5f);
        float csum = 0.f;
#pragma unroll
        for (int t = 0; t < 16; ++t) {
            const float nt = sqrtf(sA[t] + 1e-5f);
            csum += sB[t] / (nt * n15);
        }
        const float cs = csum * (1.f / 16.f);
        out[b] = 1.f / (cs + 1e-5f);
    }
}

extern "C" void kernel_launch(void* const* d_in, const int* in_sizes, int n_in,
                              void* d_out, int out_size, void* d_ws, size_t ws_size,
                              hipStream_t stream) {
    const float* x   = (const float*)d_in[0];  // [16, 32, 64, 32, 32]
    float* out       = (float*)d_out;          // [1, 32]
    float* partial   = (float*)d_ws;           // 32 * 32 * 32 floats = 128 KB

    dim3 grid1(B_DIM, NCHUNK);
    snn_pass1<<<grid1, THREADS, 0, stream>>>(x, partial);
    snn_finalize<<<B_DIM, 64, 0, stream>>>(partial, out);
}